// Round 6
// baseline (360.465 us; speedup 1.0000x reference)
//
#include <hip/hip_runtime.h>

typedef unsigned short u16;
typedef __attribute__((ext_vector_type(8))) short short8;
typedef __attribute__((ext_vector_type(4))) float f32x4;

#define N_INST 2000
#define H_DIM 256
#define D_DIM 64
#define R_DIM 49
#define LN_EPS 1e-5f
#define SPLITK 14

__device__ __forceinline__ u16 f2bf(float f) {
  union { float f; unsigned int i; } x; x.f = f;
  unsigned int r = x.i + 0x7fffu + ((x.i >> 16) & 1u);  // RNE
  return (u16)(r >> 16);
}
__device__ __forceinline__ float bf2f(u16 u) {
  union { unsigned int i; float f; } x; x.i = ((unsigned int)u) << 16; return x.f;
}
__device__ __forceinline__ short8 ld8(const u16* p) {
  return *reinterpret_cast<const short8*>(p);
}
__device__ __forceinline__ short8 pack8(float4 a, float4 b) {
  short8 r;
  r[0] = (short)f2bf(a.x); r[1] = (short)f2bf(a.y);
  r[2] = (short)f2bf(a.z); r[3] = (short)f2bf(a.w);
  r[4] = (short)f2bf(b.x); r[5] = (short)f2bf(b.y);
  r[6] = (short)f2bf(b.z); r[7] = (short)f2bf(b.w);
  return r;
}
__device__ __forceinline__ f32x4 mfma16(short8 a, short8 b, f32x4 c) {
  return __builtin_amdgcn_mfma_f32_16x16x32_bf16(a, b, c, 0, 0, 0);
}
__device__ __forceinline__ void wave_reduce2(float& s, float& s2) {
#pragma unroll
  for (int off = 32; off > 0; off >>= 1) {
    s  += __shfl_down(s, off);
    s2 += __shfl_down(s2, off);
  }
  s = __shfl(s, 0); s2 = __shfl(s2, 0);
}
// async global->LDS, 16B per lane. LDS dest lane-linear (m104).
__device__ __forceinline__ void gload16(const u16* g, u16* l) {
  __builtin_amdgcn_global_load_lds(
      (const __attribute__((address_space(1))) void*)g,
      (__attribute__((address_space(3))) void*)l, 16, 0, 0);
}

// ---------------- merged prep kernel (one launch) ----------------
// blocks [0,2048): cast_wdyn (half = b>>10)
// blocks [2048,2832): cast_wout
// blocks [2832,3332): cast_pro (grid-stride)
__global__ __launch_bounds__(256) void prep_all(
    const float* __restrict__ pro,  u16* __restrict__ proB,
    const float* __restrict__ Wdyn, u16* __restrict__ WdynT,
    const float* __restrict__ Wout, u16* __restrict__ WoutT) {
  __shared__ u16 T[64][65];
  const int tid = threadIdx.x;
  const int wave = tid >> 6, lane = tid & 63;
  const int b = blockIdx.x;
  if (b < 2048) {
    // Wdyn (256 x 32768) fp32 -> WdynT bf16 transposed+permuted:
    //  half0: WdynT[d*256+h][k]      = Wdyn[k][h*64+d]
    //  half1: WdynT[16384+h*64+d][k] = Wdyn[k][16384+d*256+h]
    const int half = b >> 10;
    const int bb = b & 1023;
    const int kt = bb >> 8;
    long colbase, rowbase; int rstride;
    if (half == 0) {
      int h = bb & 255;
      colbase = (long)h * 64; rowbase = h; rstride = 256;
    } else {
      int d = bb & 63, hc = (bb >> 6) & 3;
      colbase = 16384L + d * 256 + hc * 64;
      rowbase = 16384L + hc * 4096 + d; rstride = 64;
    }
#pragma unroll
    for (int i = 0; i < 16; ++i) {
      int kk = wave * 16 + i;
      int k = kt * 64 + kk;
      T[kk][lane] = f2bf(Wdyn[(long)k * 32768 + colbase + lane]);
    }
    __syncthreads();
#pragma unroll
    for (int i = 0; i < 16; ++i) {
      int jj = wave * 16 + i;
      long ro = rowbase + (long)jj * rstride;
      WdynT[ro * 256 + kt * 64 + lane] = T[lane][jj];
    }
  } else if (b < 2832) {
    // Wout (12544 x 256) fp32 -> WoutT (256 x 12544) bf16
    const int b2 = b - 2048;
    const int kt = b2 >> 2, ct = b2 & 3;
#pragma unroll
    for (int i = 0; i < 16; ++i) {
      int kk = wave * 16 + i;
      long k = (long)kt * 64 + kk;
      T[kk][lane] = f2bf(Wout[k * 256 + ct * 64 + lane]);
    }
    __syncthreads();
#pragma unroll
    for (int i = 0; i < 16; ++i) {
      int cc = wave * 16 + i;
      long c = (long)ct * 64 + cc;
      WoutT[c * 12544 + (long)kt * 64 + lane] = T[lane][cc];
    }
  } else {
    // pro fp32 -> bf16, 512000 floats = 128000 float4
    const int n4 = 128000;
    for (int i = (b - 2832) * 256 + tid; i < n4; i += 500 * 256) {
      float4 v = ((const float4*)pro)[i];
      u16* op = proB + i * 4;
      op[0] = f2bf(v.x); op[1] = f2bf(v.y); op[2] = f2bf(v.z); op[3] = f2bf(v.w);
    }
  }
}

// ---------------- params GEMM: full-K single-phase, 128x128 ----------------
// K=256 fits entirely in LDS: A-panel 64KB + B-panel 64KB = 128KB, 1 blk/CU.
// ONE vmcnt drain per block (vs 8 in the double-buffered loop), then 128
// MFMA/wave with no barriers. Same chunk-XOR swizzle as bmm12_ln's p1b.
// cb epilogue reuses the A-region (dead after MFMAs).
__global__ __launch_bounds__(256, 1) void gemm_pk(
    const u16* __restrict__ A,   // proB (2000 x 256) bf16
    const u16* __restrict__ BT,  // WdynT (32768 x 256) bf16
    const float* __restrict__ bias,
    u16* __restrict__ C)         // P12 (2000 x 32768) bf16
{
  __shared__ __align__(16) u16 al[128 * 256];  // 64 KB; row = 32 chunks of 16B
  __shared__ __align__(16) u16 bl[128 * 256];  // 64 KB
  const int tid = threadIdx.x;
  const int wave = tid >> 6, lane = tid & 63;
  const int quad = lane >> 4, l16 = lane & 15;
  const int wm = wave >> 1, wn = wave & 1;
  const int bid = blockIdx.x;
  const int mblk = bid >> 8, nblk = bid & 255;
  const int m0 = mblk * 128, n0 = nblk * 128;

  // ---- stage A (clamped rows) and B, full K, swizzled chunk slots ----
  // slot c of row r holds global chunk (c&24)|((c&7)^(r&7))  [involution]
#pragma unroll
  for (int j = 0; j < 16; ++j) {
    int lc = j * 256 + tid;
    int row = lc >> 5, c = lc & 31;
    int cg = (c & 24) | ((c & 7) ^ (row & 7));
    int ga = m0 + row; if (ga >= N_INST) ga = N_INST - 1;
    gload16(A + (long)ga * 256 + cg * 8, &al[lc * 8]);
  }
#pragma unroll
  for (int j = 0; j < 16; ++j) {
    int lc = j * 256 + tid;
    int row = lc >> 5, c = lc & 31;
    int cg = (c & 24) | ((c & 7) ^ (row & 7));
    gload16(BT + (long)(n0 + row) * 256 + cg * 8, &bl[lc * 8]);
  }
  // bias (combined dyn-perm), overlapped with DMA
  float bvv[4];
#pragma unroll
  for (int ni = 0; ni < 4; ++ni) {
    int col = n0 + wn * 64 + ni * 16 + l16;
    int bi = (col < 16384) ? (((col & 255) << 6) + (col >> 8))
                           : (16384 + ((col & 63) << 8) + ((col >> 6) & 255));
    bvv[ni] = bias[bi];
  }
  __syncthreads();  // single drain

  f32x4 acc[4][4];
#pragma unroll
  for (int mi = 0; mi < 4; ++mi)
#pragma unroll
    for (int ni = 0; ni < 4; ++ni) acc[mi][ni] = f32x4{0.f, 0.f, 0.f, 0.f};

  // ---- 8 ksteps x 16 MFMA, zero barriers (read-only LDS) ----
#pragma unroll
  for (int ks = 0; ks < 8; ++ks) {
    short8 av[4], bv[4];
#pragma unroll
    for (int i = 0; i < 4; ++i) {
      int q = ks * 4 + quad;
      int rt = wm * 64 + i * 16 + l16;
      int cA = (q & 24) | ((q & 7) ^ (rt & 7));
      av[i] = ld8(&al[rt * 256 + cA * 8]);
      int ct = wn * 64 + i * 16 + l16;
      int cB = (q & 24) | ((q & 7) ^ (ct & 7));
      bv[i] = ld8(&bl[ct * 256 + cB * 8]);
    }
#pragma unroll
    for (int mi = 0; mi < 4; ++mi)
#pragma unroll
      for (int ni = 0; ni < 4; ++ni)
        acc[mi][ni] = mfma16(av[mi], bv[ni], acc[mi][ni]);
  }

  __syncthreads();  // all LDS reads done; al becomes cb
  // ---- repack + bias -> cb (al), then coalesced 16B stores ----
#pragma unroll
  for (int mi = 0; mi < 4; ++mi)
#pragma unroll
    for (int ni = 0; ni < 4; ++ni)
#pragma unroll
      for (int i = 0; i < 4; ++i) {
        int row = wm * 64 + mi * 16 + quad * 4 + i;
        int col = wn * 64 + ni * 16 + l16;
        al[row * 128 + col] = f2bf(acc[mi][ni][i] + bvv[ni]);
      }
  __syncthreads();
#pragma unroll
  for (int j = 0; j < 8; ++j) {
    int lin = j * 2048 + tid * 8;
    int row = lin >> 7, col = lin & 127;
    int grow = m0 + row;
    if (grow < N_INST)
      *reinterpret_cast<short8*>(C + (long)grow * 32768 + n0 + col) =
          ld8(&al[lin]);
  }
}

// ---------------- 128x128 GEMM (used for out-GEMM, split-K) ----------------
__global__ __launch_bounds__(256, 3) void gemm128(
    const u16* __restrict__ A, int lda, int M,
    const u16* __restrict__ BT, int ldbt,
    void* __restrict__ Cout, int ldc, long c_stride_s,
    int ksteps, int n_blocks)
{
  struct Smem { u16 a[2][128 * 32]; u16 b[2][128 * 32]; };
  __shared__ Smem sm;

  const int tid = threadIdx.x;
  const int wave = tid >> 6, lane = tid & 63;
  const int quad = lane >> 4, l16 = lane & 15;
  const int wm = wave >> 1, wn = wave & 1;
  const int bid = blockIdx.x;
  const int mblk = bid / n_blocks, nblk = bid - mblk * n_blocks;
  const int m0 = mblk * 128, n0 = nblk * 128;
  const int s = blockIdx.y;
  const int kb = s * ksteps * 32;

  const int cl = tid & 3;
  const int r0 = tid >> 2, r1 = 64 + (tid >> 2);
  const int cg0 = cl ^ ((r0 >> 1) & 3);
  const int cg1 = cl ^ ((r1 >> 1) & 3);
  int ga0 = m0 + r0; if (ga0 >= M) ga0 = M - 1;
  int ga1 = m0 + r1; if (ga1 >= M) ga1 = M - 1;
  const u16* gA0 = A + (long)ga0 * lda + kb + cg0 * 8;
  const u16* gA1 = A + (long)ga1 * lda + kb + cg1 * 8;
  const u16* gB0 = BT + (long)(n0 + r0) * ldbt + kb + cg0 * 8;
  const u16* gB1 = BT + (long)(n0 + r1) * ldbt + kb + cg1 * 8;

  int fAoff[4], fBoff[4];
#pragma unroll
  for (int i = 0; i < 4; ++i) {
    int rt = wm * 64 + i * 16 + l16;
    fAoff[i] = rt * 32 + (quad ^ ((rt >> 1) & 3)) * 8;
    int ct = wn * 64 + i * 16 + l16;
    fBoff[i] = ct * 32 + (quad ^ ((ct >> 1) & 3)) * 8;
  }

  f32x4 acc[4][4];
#pragma unroll
  for (int mi = 0; mi < 4; ++mi)
#pragma unroll
    for (int ni = 0; ni < 4; ++ni) acc[mi][ni] = f32x4{0.f, 0.f, 0.f, 0.f};

  gload16(gA0, &sm.a[0][tid * 8]);
  gload16(gA1, &sm.a[0][(tid + 256) * 8]);
  gload16(gB0, &sm.b[0][tid * 8]);
  gload16(gB1, &sm.b[0][(tid + 256) * 8]);

  for (int ks = 0; ks < ksteps; ++ks) {
    const int cur = ks & 1, nxt = cur ^ 1;
    __syncthreads();
    if (ks + 1 < ksteps) {
      const int ko = (ks + 1) * 32;
      gload16(gA0 + ko, &sm.a[nxt][tid * 8]);
      gload16(gA1 + ko, &sm.a[nxt][(tid + 256) * 8]);
      gload16(gB0 + ko, &sm.b[nxt][tid * 8]);
      gload16(gB1 + ko, &sm.b[nxt][(tid + 256) * 8]);
    }
    short8 av[4], bv[4];
#pragma unroll
    for (int i = 0; i < 4; ++i) {
      av[i] = ld8(&sm.a[cur][fAoff[i]]);
      bv[i] = ld8(&sm.b[cur][fBoff[i]]);
    }
#pragma unroll
    for (int mi = 0; mi < 4; ++mi)
#pragma unroll
      for (int ni = 0; ni < 4; ++ni)
        acc[mi][ni] = mfma16(av[mi], bv[ni], acc[mi][ni]);
  }

  float* Cp = (float*)Cout + (long)s * c_stride_s;
#pragma unroll
  for (int mi = 0; mi < 4; ++mi)
#pragma unroll
    for (int ni = 0; ni < 4; ++ni) {
      int col = n0 + wn * 64 + ni * 16 + l16;
#pragma unroll
      for (int i = 0; i < 4; ++i) {
        int row = m0 + wm * 64 + mi * 16 + quad * 4 + i;
        if (row < M) Cp[(long)row * ldc + col] = acc[mi][ni][i];
      }
    }
}

// ---------------- fused bmm1+LN1+bmm2+LN2 (R2 structure) ----------------
// One block per instance. P12[n] = [p1T [d][h] 32KB | p2T [h][d] 32KB].
// P2 is NOT LDS-staged: bmm2 is h-split across waves (wave w owns h in
// [64w,64w+64)); the wave's disjoint 8KB P2 slice loads global->VGPR
// (pf[4][2]) in the upfront burst. LDS = p1b 32K + f1b 8K = 40KB ->
// 4 blocks/CU. LN2 cross-wave reduce via stats in the dead tail of p1b.
__global__ __launch_bounds__(256, 4) void bmm12_ln(
    const float* __restrict__ roi,  // (R, N, H) fp32
    const u16* __restrict__ P12,    // (N, 32768) bf16
    const float* __restrict__ g1, const float* __restrict__ b1,
    const float* __restrict__ g2, const float* __restrict__ b2,
    u16* __restrict__ f2n)          // (N, R, H) bf16
{
  __shared__ __align__(16) u16 p1b[16384];  // 32 KB: P1 -> cb2 -> stats tail
  __shared__ __align__(16) u16 f1b[4096];   // 8 KB: LN1 output (swizzled)
  const int n = blockIdx.x;
  const int tid = threadIdx.x;
  const int wave = tid >> 6, lane = tid & 63;
  const int quad = lane >> 4, l16 = lane & 15;
  const int wstripe = wave * 16;

  // ---- upfront burst: P1 DMA -> p1b, roi -> regs (packed), P2 -> regs ----
  const u16* P1n = P12 + (long)n * 32768;
#pragma unroll
  for (int j = 0; j < 8; ++j) {
    int lc = j * 256 + tid;
    int d = lc >> 5, c = lc & 31;
    int cg = (c & 24) | ((c & 7) ^ (d & 7));
    gload16(P1n + d * 256 + cg * 8, &p1b[lc * 8]);
  }
  int r = wstripe + l16;
  int rr = (r < R_DIM) ? r : 0;
  const float* Arow = roi + ((long)rr * N_INST + n) * H_DIM + quad * 8;
  short8 sa[8];
#pragma unroll
  for (int ks = 0; ks < 8; ++ks) {
    float4 va = ((const float4*)(Arow + ks * 32))[0];
    float4 vb = ((const float4*)(Arow + ks * 32))[1];
    sa[ks] = pack8(va, vb);
  }
  const u16* P2n = P12 + (long)n * 32768 + 16384;
  short8 pf[4][2];
#pragma unroll
  for (int hs = 0; hs < 4; ++hs)
#pragma unroll
    for (int ks = 0; ks < 2; ++ks) {
      int h = wave * 64 + hs * 16 + l16;
      pf[hs][ks] = ld8(P2n + h * 64 + (ks * 4 + quad) * 8);
    }
  float gv1[4], bv1[4];
#pragma unroll
  for (int sub = 0; sub < 4; ++sub) {
    gv1[sub] = g1[sub * 16 + l16]; bv1[sub] = b1[sub * 16 + l16];
  }
  __syncthreads();  // barrier 1: p1b DMA drained

  // ---- bmm1: C1[r][d], wave stripe rows wstripe+0..15 ----
  f32x4 acc1[4];
#pragma unroll
  for (int i = 0; i < 4; ++i) acc1[i] = f32x4{0.f, 0.f, 0.f, 0.f};
#pragma unroll
  for (int ks = 0; ks < 8; ++ks) {
#pragma unroll
    for (int sub = 0; sub < 4; ++sub) {
      int d = sub * 16 + l16;
      int q = ks * 4 + quad;
      int c = (q & 24) | ((q & 7) ^ (d & 7));
      acc1[sub] = mfma16(sa[ks], ld8(&p1b[d * 256 + c * 8]), acc1[sub]);
    }
  }

  // ---- LN1 on acc1: stats over D=64 = (4 subs) x (16 lanes of quad) ----
  {
    float s1[4], s2[4];
#pragma unroll
    for (int i = 0; i < 4; ++i) {
      s1[i] = 0.f; s2[i] = 0.f;
#pragma unroll
      for (int sub = 0; sub < 4; ++sub) {
        float v = acc1[sub][i]; s1[i] += v; s2[i] += v * v;
      }
    }
#pragma unroll
    for (int m = 1; m < 16; m <<= 1)
#pragma unroll
      for (int i = 0; i < 4; ++i) {
        s1[i] += __shfl_xor(s1[i], m, 16);
        s2[i] += __shfl_xor(s2[i], m, 16);
      }
#pragma unroll
    for (int i = 0; i < 4; ++i) {
      float mean = s1[i] * (1.f / 64.f);
      float var = s2[i] * (1.f / 64.f) - mean * mean;
      float rs = rsqrtf(var + LN_EPS);
      int row = wstripe + quad * 4 + i;
#pragma unroll
      for (int sub = 0; sub < 4; ++sub) {
        float y = fmaxf((acc1[sub][i] - mean) * rs * gv1[sub] + bv1[sub], 0.f);
        int kc = (sub * 2 + (l16 >> 3)) ^ (row & 7);
        f1b[row * 64 + kc * 8 + (l16 & 7)] = f2bf(y);
      }
    }
  }
  __syncthreads();  // barrier 2: f1b visible to ALL waves (h-split bmm2)

  // ---- bmm2 (h-split): wave w computes C2[all 64 r][h in 64w..64w+63] ----
  f32x4 acc2[4][4];  // [rs][hs]
#pragma unroll
  for (int rs = 0; rs < 4; ++rs)
#pragma unroll
    for (int hs = 0; hs < 4; ++hs) acc2[rs][hs] = f32x4{0.f, 0.f, 0.f, 0.f};
#pragma unroll
  for (int ks = 0; ks < 2; ++ks) {
#pragma unroll
    for (int rs = 0; rs < 4; ++rs) {
      int row = rs * 16 + l16;
      int c2 = (ks * 4 + quad) ^ (row & 7);
      short8 af = ld8(&f1b[row * 64 + c2 * 8]);
#pragma unroll
      for (int hs = 0; hs < 4; ++hs)
        acc2[rs][hs] = mfma16(af, pf[hs][ks], acc2[rs][hs]);
    }
  }

  // ---- LN2: per-row stats over H=256, split across waves (64 h each) ----
  float s1[4][4], s2[4][4];
#pragma unroll
  for (int rs = 0; rs < 4; ++rs)
#pragma unroll
    for (int i = 0; i < 4; ++i) {
      float a = 0.f, b = 0.f;
#pragma unroll
      for (int hs = 0; hs < 4; ++hs) {
        float v = acc2[rs][hs][i]; a += v; b += v * v;
      }
      s1[rs][i] = a; s2[rs][i] = b;
    }
#pragma unroll
  for (int m = 1; m < 16; m <<= 1)
#pragma unroll
    for (int rs = 0; rs < 4; ++rs)
#pragma unroll
      for (int i = 0; i < 4; ++i) {
        s1[rs][i] += __shfl_xor(s1[rs][i], m, 16);
        s2[rs][i] += __shfl_xor(s2[rs][i], m, 16);
      }
  float2* lnst = reinterpret_cast<float2*>(&p1b[14336]);
  if (l16 == 0) {
#pragma unroll
    for (int rs = 0; rs < 4; ++rs)
#pragma unroll
      for (int i = 0; i < 4; ++i) {
        int row = rs * 16 + quad * 4 + i;
        lnst[row * 4 + wave] = float2{s1[rs][i], s2[rs][i]};
      }
  }
  __syncthreads();  // barrier 3: stats visible

  // ---- finalize LN2 + write normalized z -> cb2 (p1b, stride 264) ----
#pragma unroll
  for (int rs = 0; rs < 4; ++rs)
#pragma unroll
    for (int i = 0; i < 4; ++i) {
      int row = rs * 16 + quad * 4 + i;
      f32x4 qa = *reinterpret_cast<const f32x4*>(&lnst[row * 4]);
      f32x4 qb = *reinterpret_cast<const f32x4*>(&lnst[row * 4 + 2]);
      float S1 = qa[0] + qa[2] + qb[0] + qb[2];
      float S2 = qa[1] + qa[3] + qb[1] + qb[3];
      float mean = S1 * (1.f / 256.f);
      float var = S2 * (1.f / 256.f) - mean * mean;
      float rsq = rsqrtf(var + LN_EPS);
      if (row < R_DIM) {
#pragma unroll
        for (int hs = 0; hs < 4; ++hs)
          p1b[row * 264 + wave * 64 + hs * 16 + l16] =
              f2bf((acc2[rs][hs][i] - mean) * rsq);
      }
    }
  __syncthreads();  // barrier 4: cb2 visible

  // ---- epilogue copy: y = relu(z*g2 + b2), vectorized stores ----
  u16* f2out = f2n + (long)n * (R_DIM * H_DIM);
  for (int t = tid; t < R_DIM * 32; t += 256) {
    int row = t >> 5, c = t & 31;
    short8 z8 = ld8(&p1b[row * 264 + c * 8]);
    const float4* gp = (const float4*)(g2 + c * 8);
    const float4* bp = (const float4*)(b2 + c * 8);
    float4 ga = gp[0], gb = gp[1], ba = bp[0], bb = bp[1];
    short8 y;
    y[0] = (short)f2bf(fmaxf(bf2f((u16)z8[0]) * ga.x + ba.x, 0.f));
    y[1] = (short)f2bf(fmaxf(bf2f((u16)z8[1]) * ga.y + ba.y, 0.f));
    y[2] = (short)f2bf(fmaxf(bf2f((u16)z8[2]) * ga.z + ba.z, 0.f));
    y[3] = (short)f2bf(fmaxf(bf2f((u16)z8[3]) * ga.w + ba.w, 0.f));
    y[4] = (short)f2bf(fmaxf(bf2f((u16)z8[4]) * gb.x + bb.x, 0.f));
    y[5] = (short)f2bf(fmaxf(bf2f((u16)z8[5]) * gb.y + bb.y, 0.f));
    y[6] = (short)f2bf(fmaxf(bf2f((u16)z8[6]) * gb.z + bb.z, 0.f));
    y[7] = (short)f2bf(fmaxf(bf2f((u16)z8[7]) * gb.w + bb.w, 0.f));
    *reinterpret_cast<short8*>(f2out + row * 256 + c * 8) = y;
  }
}

// Sum split-K partials + bias, LN over H, ReLU -> fp32 out. One wave per row.
__global__ __launch_bounds__(64) void ln3_k(
    const float* __restrict__ partial,  // (SPLITK, N, H) fp32
    const float* __restrict__ b_out,
    const float* __restrict__ g3, const float* __restrict__ b3,
    float* __restrict__ out)            // (N, H) fp32
{
  const int n = blockIdx.x;
  const int lane = threadIdx.x;
  float x[4], sv = 0.f, s2 = 0.f;
#pragma unroll
  for (int j = 0; j < 4; ++j) {
    int h = lane + 64 * j;
    float v = b_out[h];
#pragma unroll
    for (int ss = 0; ss < SPLITK; ++ss)
      v += partial[((long)ss * N_INST + n) * H_DIM + h];
    x[j] = v; sv += v; s2 += v * v;
  }
  wave_reduce2(sv, s2);
  float mean = sv * (1.f / 256.f);
  float var = s2 * (1.f / 256.f) - mean * mean;
  float rs = rsqrtf(var + LN_EPS);
#pragma unroll
  for (int j = 0; j < 4; ++j) {
    int h = lane + 64 * j;
    float y = fmaxf((x[j] - mean) * rs * g3[h] + b3[h], 0.f);
    out[(long)n * H_DIM + h] = y;
  }
}

extern "C" void kernel_launch(void* const* d_in, const int* in_sizes, int n_in,
                              void* d_out, int out_size, void* d_ws, size_t ws_size,
                              hipStream_t stream) {
  const float* pro  = (const float*)d_in[0];
  const float* roi  = (const float*)d_in[1];
  const float* Wdyn = (const float*)d_in[2];
  const float* bdyn = (const float*)d_in[3];
  const float* Wout = (const float*)d_in[4];
  const float* bout = (const float*)d_in[5];
  const float* g1 = (const float*)d_in[6];
  const float* b1 = (const float*)d_in[7];
  const float* g2 = (const float*)d_in[8];
  const float* b2 = (const float*)d_in[9];
  const float* g3 = (const float*)d_in[10];
  const float* b3 = (const float*)d_in[11];
  float* out = (float*)d_out;

  // ws layout (bytes):
  //   proB  @ 0          : 1,024,000
  //   WdynT @ 1,024,000  : 16,777,216
  //   WoutT @ 17,801,216 : 6,422,528
  //   P12   @ 24,223,744 : 131,072,000 (2000 x [p1T|p2T]; partial aliases)
  //   f2n   @ 155,295,744: 50,176,000
  char* ws = (char*)d_ws;
  u16* proB  = (u16*)ws;
  u16* WdynT = (u16*)(ws + 1024000);
  u16* WoutT = (u16*)(ws + 17801216);
  u16* P12   = (u16*)(ws + 24223744);
  u16* f2n   = (u16*)(ws + 155295744);
  float* partial = (float*)(ws + 24223744);

  dim3 blk(256);

  // merged prep: wdyn transpose (2048) + wout transpose (784) + pro cast (500)
  prep_all<<<dim3(3332), blk, 0, stream>>>(pro, proB, Wdyn, WdynT, Wout, WoutT);

  // params: (2000x256)@(256x32768) -> P12, full-K single-phase 128x128
  gemm_pk<<<dim3(4096), blk, 0, stream>>>(proB, WdynT, bdyn, P12);

  // fused bmm1+LN1+bmm2+LN2
  bmm12_ln<<<dim3(N_INST), blk, 0, stream>>>(roi, P12, g1, b1, g2, b2, f2n);

  // out GEMM: (2000x12544)@(12544x256), split-K=14 (28 ksteps)
  gemm128<<<dim3(16 * 2, SPLITK), blk, 0, stream>>>(
      f2n, R_DIM * H_DIM, N_INST, WoutT, R_DIM * H_DIM,
      (void*)partial, H_DIM, (long)N_INST * H_DIM, 28, 2);

  ln3_k<<<dim3(N_INST), dim3(64), 0, stream>>>(partial, bout, g3, b3, out);
}

// Round 7
// 330.905 us; speedup vs baseline: 1.0893x; 1.0893x over previous
//
#include <hip/hip_runtime.h>

typedef unsigned short u16;
typedef __attribute__((ext_vector_type(8))) short short8;
typedef __attribute__((ext_vector_type(4))) float f32x4;

#define N_INST 2000
#define H_DIM 256
#define D_DIM 64
#define R_DIM 49
#define LN_EPS 1e-5f
#define SPLITK 14
#define NBUF 5

__device__ __forceinline__ u16 f2bf(float f) {
  union { float f; unsigned int i; } x; x.f = f;
  unsigned int r = x.i + 0x7fffu + ((x.i >> 16) & 1u);  // RNE
  return (u16)(r >> 16);
}
__device__ __forceinline__ float bf2f(u16 u) {
  union { unsigned int i; float f; } x; x.i = ((unsigned int)u) << 16; return x.f;
}
__device__ __forceinline__ short8 ld8(const u16* p) {
  return *reinterpret_cast<const short8*>(p);
}
__device__ __forceinline__ short8 pack8(float4 a, float4 b) {
  short8 r;
  r[0] = (short)f2bf(a.x); r[1] = (short)f2bf(a.y);
  r[2] = (short)f2bf(a.z); r[3] = (short)f2bf(a.w);
  r[4] = (short)f2bf(b.x); r[5] = (short)f2bf(b.y);
  r[6] = (short)f2bf(b.z); r[7] = (short)f2bf(b.w);
  return r;
}
__device__ __forceinline__ f32x4 mfma16(short8 a, short8 b, f32x4 c) {
  return __builtin_amdgcn_mfma_f32_16x16x32_bf16(a, b, c, 0, 0, 0);
}
// async global->LDS, 16B per lane. LDS dest lane-linear (m104).
__device__ __forceinline__ void gload16(const u16* g, u16* l) {
  __builtin_amdgcn_global_load_lds(
      (const __attribute__((address_space(1))) void*)g,
      (__attribute__((address_space(3))) void*)l, 16, 0, 0);
}

// ---------------- merged prep kernel (one launch) ----------------
// blocks [0,2048): cast_wdyn (half = b>>10)
// blocks [2048,2832): cast_wout
// blocks [2832,3332): cast_pro (grid-stride)
__global__ __launch_bounds__(256) void prep_all(
    const float* __restrict__ pro,  u16* __restrict__ proB,
    const float* __restrict__ Wdyn, u16* __restrict__ WdynT,
    const float* __restrict__ Wout, u16* __restrict__ WoutT) {
  __shared__ u16 T[64][65];
  const int tid = threadIdx.x;
  const int wave = tid >> 6, lane = tid & 63;
  const int b = blockIdx.x;
  if (b < 2048) {
    // Wdyn (256 x 32768) fp32 -> WdynT bf16 transposed+permuted:
    //  half0: WdynT[d*256+h][k]      = Wdyn[k][h*64+d]
    //  half1: WdynT[16384+h*64+d][k] = Wdyn[k][16384+d*256+h]
    const int half = b >> 10;
    const int bb = b & 1023;
    const int kt = bb >> 8;
    long colbase, rowbase; int rstride;
    if (half == 0) {
      int h = bb & 255;
      colbase = (long)h * 64; rowbase = h; rstride = 256;
    } else {
      int d = bb & 63, hc = (bb >> 6) & 3;
      colbase = 16384L + d * 256 + hc * 64;
      rowbase = 16384L + hc * 4096 + d; rstride = 64;
    }
#pragma unroll
    for (int i = 0; i < 16; ++i) {
      int kk = wave * 16 + i;
      int k = kt * 64 + kk;
      T[kk][lane] = f2bf(Wdyn[(long)k * 32768 + colbase + lane]);
    }
    __syncthreads();
#pragma unroll
    for (int i = 0; i < 16; ++i) {
      int jj = wave * 16 + i;
      long ro = rowbase + (long)jj * rstride;
      WdynT[ro * 256 + kt * 64 + lane] = T[lane][jj];
    }
  } else if (b < 2832) {
    // Wout (12544 x 256) fp32 -> WoutT (256 x 12544) bf16
    const int b2 = b - 2048;
    const int kt = b2 >> 2, ct = b2 & 3;
#pragma unroll
    for (int i = 0; i < 16; ++i) {
      int kk = wave * 16 + i;
      long k = (long)kt * 64 + kk;
      T[kk][lane] = f2bf(Wout[k * 256 + ct * 64 + lane]);
    }
    __syncthreads();
#pragma unroll
    for (int i = 0; i < 16; ++i) {
      int cc = wave * 16 + i;
      long c = (long)ct * 64 + cc;
      WoutT[c * 12544 + (long)kt * 64 + lane] = T[lane][cc];
    }
  } else {
    // pro fp32 -> bf16, 512000 floats = 128000 float4
    const int n4 = 128000;
    for (int i = (b - 2832) * 256 + tid; i < n4; i += 500 * 256) {
      float4 v = ((const float4*)pro)[i];
      u16* op = proB + i * 4;
      op[0] = f2bf(v.x); op[1] = f2bf(v.y); op[2] = f2bf(v.z); op[3] = f2bf(v.w);
    }
  }
}

// ---------------- 128x128 GEMM, counted-vmcnt pipeline ----------------
// NBUF=5 staging buffers (80KB LDS -> 2 blocks/CU), lookahead-3:
// iter ks stages k-group ks+3 into slot (ks+3)%5, waits vmcnt(12/8/4/0)
// (never drains mid-loop), raw s_barrier, computes slot ks%5.
// Race safety: barrier/iter bounds wave skew to 1 iter; staged slot is
// always >=2 slots from any slot still being read (distance 4 mod 5).
// Bias is loaded AFTER the loop so it never perturbs the vmcnt counts.
// bias_mode: 0 direct, 3 combined dyn-perm. out_f32: splitk fp32 path.
__global__ __launch_bounds__(256, 2) void gemm128(
    const u16* __restrict__ A, int lda, int M,
    const u16* __restrict__ BT, int ldbt,
    const float* __restrict__ bias, int bias_mode,
    void* __restrict__ Cout, int ldc, long c_stride_s,
    int ksteps, int n_blocks, int out_f32)
{
  union Smem {
    struct { u16 a[NBUF][128 * 32]; u16 b[NBUF][128 * 32]; } s;  // 80 KB
    u16 cb[128 * 128];  // 32 KB (aliases slots 0-1 of a)
  };
  __shared__ Smem sm;

  const int tid = threadIdx.x;
  const int wave = tid >> 6, lane = tid & 63;
  const int quad = lane >> 4, l16 = lane & 15;
  const int wm = wave >> 1, wn = wave & 1;
  const int bid = blockIdx.x;
  const int mblk = bid / n_blocks, nblk = bid - mblk * n_blocks;
  const int m0 = mblk * 128, n0 = nblk * 128;
  const int s = blockIdx.y;
  const int kb = s * ksteps * 32;

  const int cl = tid & 3;
  const int r0 = tid >> 2, r1 = 64 + (tid >> 2);
  const int cg0 = cl ^ ((r0 >> 1) & 3);
  const int cg1 = cl ^ ((r1 >> 1) & 3);
  int ga0 = m0 + r0; if (ga0 >= M) ga0 = M - 1;
  int ga1 = m0 + r1; if (ga1 >= M) ga1 = M - 1;
  const u16* gA0 = A + (long)ga0 * lda + kb + cg0 * 8;
  const u16* gA1 = A + (long)ga1 * lda + kb + cg1 * 8;
  const u16* gB0 = BT + (long)(n0 + r0) * ldbt + kb + cg0 * 8;
  const u16* gB1 = BT + (long)(n0 + r1) * ldbt + kb + cg1 * 8;

  int fAoff[4], fBoff[4];
#pragma unroll
  for (int i = 0; i < 4; ++i) {
    int rt = wm * 64 + i * 16 + l16;
    fAoff[i] = rt * 32 + (quad ^ ((rt >> 1) & 3)) * 8;
    int ct = wn * 64 + i * 16 + l16;
    fBoff[i] = ct * 32 + (quad ^ ((ct >> 1) & 3)) * 8;
  }

  f32x4 acc[4][4];
#pragma unroll
  for (int mi = 0; mi < 4; ++mi)
#pragma unroll
    for (int ni = 0; ni < 4; ++ni) acc[mi][ni] = f32x4{0.f, 0.f, 0.f, 0.f};

  auto stage = [&](int slot, int kg) {
    const int ko = kg * 32;
    gload16(gA0 + ko, &sm.s.a[slot][tid * 8]);
    gload16(gA1 + ko, &sm.s.a[slot][(tid + 256) * 8]);
    gload16(gB0 + ko, &sm.s.b[slot][tid * 8]);
    gload16(gB1 + ko, &sm.s.b[slot][(tid + 256) * 8]);
  };

  // prologue: stage k-groups 0,1,2 (ksteps >= 3 for all call sites)
  stage(0, 0); stage(1, 1); stage(2, 2);
  int sk = 3, ssl = 3, sc = 0;

  for (int ks = 0; ks < ksteps; ++ks) {
    if (sk < ksteps) {
      stage(ssl, sk);
      ++sk; if (++ssl == NBUF) ssl = 0;
    }
    const int rem = (sk - ks - 1) * 4;  // loads allowed to stay in flight
    if (rem >= 12)     asm volatile("s_waitcnt vmcnt(12)" ::: "memory");
    else if (rem == 8) asm volatile("s_waitcnt vmcnt(8)" ::: "memory");
    else if (rem == 4) asm volatile("s_waitcnt vmcnt(4)" ::: "memory");
    else               asm volatile("s_waitcnt vmcnt(0)" ::: "memory");
    __builtin_amdgcn_s_barrier();
    short8 av[4], bv[4];
#pragma unroll
    for (int i = 0; i < 4; ++i) {
      av[i] = ld8(&sm.s.a[sc][fAoff[i]]);
      bv[i] = ld8(&sm.s.b[sc][fBoff[i]]);
    }
#pragma unroll
    for (int mi = 0; mi < 4; ++mi)
#pragma unroll
      for (int ni = 0; ni < 4; ++ni)
        acc[mi][ni] = mfma16(av[mi], bv[ni], acc[mi][ni]);
    if (++sc == NBUF) sc = 0;
  }

  if (!out_f32) {
    __syncthreads();  // all LDS reads done; cb may overwrite staging
    float bvv[4];
#pragma unroll
    for (int ni = 0; ni < 4; ++ni) {
      int col = n0 + wn * 64 + ni * 16 + l16;
      int bi = col;
      if (bias_mode == 3)
        bi = (col < 16384) ? (((col & 255) << 6) + (col >> 8))
                           : (16384 + ((col & 63) << 8) + ((col >> 6) & 255));
      bvv[ni] = bias ? bias[bi] : 0.f;
    }
#pragma unroll
    for (int mi = 0; mi < 4; ++mi)
#pragma unroll
      for (int ni = 0; ni < 4; ++ni)
#pragma unroll
        for (int i = 0; i < 4; ++i) {
          int row = wm * 64 + mi * 16 + quad * 4 + i;
          int col = wn * 64 + ni * 16 + l16;
          sm.cb[row * 128 + col] = f2bf(acc[mi][ni][i] + bvv[ni]);
        }
    __syncthreads();
    u16* Cp = (u16*)Cout;
#pragma unroll
    for (int j = 0; j < 8; ++j) {
      int lin = j * 2048 + tid * 8;
      int row = lin >> 7, col = lin & 127;
      int grow = m0 + row;
      if (grow < M)
        *reinterpret_cast<short8*>(Cp + (long)grow * ldc + n0 + col) =
            ld8(&sm.cb[lin]);
    }
  } else {
    float* Cp = (float*)Cout + (long)s * c_stride_s;
#pragma unroll
    for (int mi = 0; mi < 4; ++mi)
#pragma unroll
      for (int ni = 0; ni < 4; ++ni) {
        int col = n0 + wn * 64 + ni * 16 + l16;
#pragma unroll
        for (int i = 0; i < 4; ++i) {
          int row = m0 + wm * 64 + mi * 16 + quad * 4 + i;
          if (row < M) Cp[(long)row * ldc + col] = acc[mi][ni][i];
        }
      }
  }
}

// ---------------- fused bmm1+LN1+bmm2+LN2 (R2 structure) ----------------
// One block per instance. P12[n] = [p1T [d][h] 32KB | p2T [h][d] 32KB].
// P2 is NOT LDS-staged: bmm2 is h-split across waves (wave w owns h in
// [64w,64w+64)); the wave's disjoint 8KB P2 slice loads global->VGPR
// (pf[4][2]) in the upfront burst. LDS = p1b 32K + f1b 8K = 40KB ->
// 4 blocks/CU. LN2 cross-wave reduce via stats in the dead tail of p1b.
__global__ __launch_bounds__(256, 4) void bmm12_ln(
    const float* __restrict__ roi,  // (R, N, H) fp32
    const u16* __restrict__ P12,    // (N, 32768) bf16
    const float* __restrict__ g1, const float* __restrict__ b1,
    const float* __restrict__ g2, const float* __restrict__ b2,
    u16* __restrict__ f2n)          // (N, R, H) bf16
{
  __shared__ __align__(16) u16 p1b[16384];  // 32 KB: P1 -> cb2 -> stats tail
  __shared__ __align__(16) u16 f1b[4096];   // 8 KB: LN1 output (swizzled)
  const int n = blockIdx.x;
  const int tid = threadIdx.x;
  const int wave = tid >> 6, lane = tid & 63;
  const int quad = lane >> 4, l16 = lane & 15;
  const int wstripe = wave * 16;

  // ---- upfront burst: P1 DMA -> p1b, roi -> regs (packed), P2 -> regs ----
  const u16* P1n = P12 + (long)n * 32768;
#pragma unroll
  for (int j = 0; j < 8; ++j) {
    int lc = j * 256 + tid;
    int d = lc >> 5, c = lc & 31;
    int cg = (c & 24) | ((c & 7) ^ (d & 7));
    gload16(P1n + d * 256 + cg * 8, &p1b[lc * 8]);
  }
  int r = wstripe + l16;
  int rr = (r < R_DIM) ? r : 0;
  const float* Arow = roi + ((long)rr * N_INST + n) * H_DIM + quad * 8;
  short8 sa[8];
#pragma unroll
  for (int ks = 0; ks < 8; ++ks) {
    float4 va = ((const float4*)(Arow + ks * 32))[0];
    float4 vb = ((const float4*)(Arow + ks * 32))[1];
    sa[ks] = pack8(va, vb);
  }
  const u16* P2n = P12 + (long)n * 32768 + 16384;
  short8 pf[4][2];
#pragma unroll
  for (int hs = 0; hs < 4; ++hs)
#pragma unroll
    for (int ks = 0; ks < 2; ++ks) {
      int h = wave * 64 + hs * 16 + l16;
      pf[hs][ks] = ld8(P2n + h * 64 + (ks * 4 + quad) * 8);
    }
  float gv1[4], bv1[4];
#pragma unroll
  for (int sub = 0; sub < 4; ++sub) {
    gv1[sub] = g1[sub * 16 + l16]; bv1[sub] = b1[sub * 16 + l16];
  }
  __syncthreads();  // barrier 1: p1b DMA drained

  // ---- bmm1: C1[r][d], wave stripe rows wstripe+0..15 ----
  f32x4 acc1[4];
#pragma unroll
  for (int i = 0; i < 4; ++i) acc1[i] = f32x4{0.f, 0.f, 0.f, 0.f};
#pragma unroll
  for (int ks = 0; ks < 8; ++ks) {
#pragma unroll
    for (int sub = 0; sub < 4; ++sub) {
      int d = sub * 16 + l16;
      int q = ks * 4 + quad;
      int c = (q & 24) | ((q & 7) ^ (d & 7));
      acc1[sub] = mfma16(sa[ks], ld8(&p1b[d * 256 + c * 8]), acc1[sub]);
    }
  }

  // ---- LN1 on acc1: stats over D=64 = (4 subs) x (16 lanes of quad) ----
  {
    float s1[4], s2[4];
#pragma unroll
    for (int i = 0; i < 4; ++i) {
      s1[i] = 0.f; s2[i] = 0.f;
#pragma unroll
      for (int sub = 0; sub < 4; ++sub) {
        float v = acc1[sub][i]; s1[i] += v; s2[i] += v * v;
      }
    }
#pragma unroll
    for (int m = 1; m < 16; m <<= 1)
#pragma unroll
      for (int i = 0; i < 4; ++i) {
        s1[i] += __shfl_xor(s1[i], m, 16);
        s2[i] += __shfl_xor(s2[i], m, 16);
      }
#pragma unroll
    for (int i = 0; i < 4; ++i) {
      float mean = s1[i] * (1.f / 64.f);
      float var = s2[i] * (1.f / 64.f) - mean * mean;
      float rs = rsqrtf(var + LN_EPS);
      int row = wstripe + quad * 4 + i;
#pragma unroll
      for (int sub = 0; sub < 4; ++sub) {
        float y = fmaxf((acc1[sub][i] - mean) * rs * gv1[sub] + bv1[sub], 0.f);
        int kc = (sub * 2 + (l16 >> 3)) ^ (row & 7);
        f1b[row * 64 + kc * 8 + (l16 & 7)] = f2bf(y);
      }
    }
  }
  __syncthreads();  // barrier 2: f1b visible to ALL waves (h-split bmm2)

  // ---- bmm2 (h-split): wave w computes C2[all 64 r][h in 64w..64w+63] ----
  f32x4 acc2[4][4];  // [rs][hs]
#pragma unroll
  for (int rs = 0; rs < 4; ++rs)
#pragma unroll
    for (int hs = 0; hs < 4; ++hs) acc2[rs][hs] = f32x4{0.f, 0.f, 0.f, 0.f};
#pragma unroll
  for (int ks = 0; ks < 2; ++ks) {
#pragma unroll
    for (int rs = 0; rs < 4; ++rs) {
      int row = rs * 16 + l16;
      int c2 = (ks * 4 + quad) ^ (row & 7);
      short8 af = ld8(&f1b[row * 64 + c2 * 8]);
#pragma unroll
      for (int hs = 0; hs < 4; ++hs)
        acc2[rs][hs] = mfma16(af, pf[hs][ks], acc2[rs][hs]);
    }
  }

  // ---- LN2: per-row stats over H=256, split across waves (64 h each) ----
  float s1[4][4], s2[4][4];
#pragma unroll
  for (int rs = 0; rs < 4; ++rs)
#pragma unroll
    for (int i = 0; i < 4; ++i) {
      float a = 0.f, b = 0.f;
#pragma unroll
      for (int hs = 0; hs < 4; ++hs) {
        float v = acc2[rs][hs][i]; a += v; b += v * v;
      }
      s1[rs][i] = a; s2[rs][i] = b;
    }
#pragma unroll
  for (int m = 1; m < 16; m <<= 1)
#pragma unroll
    for (int rs = 0; rs < 4; ++rs)
#pragma unroll
      for (int i = 0; i < 4; ++i) {
        s1[rs][i] += __shfl_xor(s1[rs][i], m, 16);
        s2[rs][i] += __shfl_xor(s2[rs][i], m, 16);
      }
  float2* lnst = reinterpret_cast<float2*>(&p1b[14336]);
  if (l16 == 0) {
#pragma unroll
    for (int rs = 0; rs < 4; ++rs)
#pragma unroll
      for (int i = 0; i < 4; ++i) {
        int row = rs * 16 + quad * 4 + i;
        lnst[row * 4 + wave] = float2{s1[rs][i], s2[rs][i]};
      }
  }
  __syncthreads();  // barrier 3: stats visible

  // ---- finalize LN2 + write normalized z -> cb2 (p1b, stride 264) ----
#pragma unroll
  for (int rs = 0; rs < 4; ++rs)
#pragma unroll
    for (int i = 0; i < 4; ++i) {
      int row = rs * 16 + quad * 4 + i;
      f32x4 qa = *reinterpret_cast<const f32x4*>(&lnst[row * 4]);
      f32x4 qb = *reinterpret_cast<const f32x4*>(&lnst[row * 4 + 2]);
      float S1 = qa[0] + qa[2] + qb[0] + qb[2];
      float S2 = qa[1] + qa[3] + qb[1] + qb[3];
      float mean = S1 * (1.f / 256.f);
      float var = S2 * (1.f / 256.f) - mean * mean;
      float rsq = rsqrtf(var + LN_EPS);
      if (row < R_DIM) {
#pragma unroll
        for (int hs = 0; hs < 4; ++hs)
          p1b[row * 264 + wave * 64 + hs * 16 + l16] =
              f2bf((acc2[rs][hs][i] - mean) * rsq);
      }
    }
  __syncthreads();  // barrier 4: cb2 visible

  // ---- epilogue copy: y = relu(z*g2 + b2), vectorized stores ----
  u16* f2out = f2n + (long)n * (R_DIM * H_DIM);
  for (int t = tid; t < R_DIM * 32; t += 256) {
    int row = t >> 5, c = t & 31;
    short8 z8 = ld8(&p1b[row * 264 + c * 8]);
    const float4* gp = (const float4*)(g2 + c * 8);
    const float4* bp = (const float4*)(b2 + c * 8);
    float4 ga = gp[0], gb = gp[1], ba = bp[0], bb = bp[1];
    short8 y;
    y[0] = (short)f2bf(fmaxf(bf2f((u16)z8[0]) * ga.x + ba.x, 0.f));
    y[1] = (short)f2bf(fmaxf(bf2f((u16)z8[1]) * ga.y + ba.y, 0.f));
    y[2] = (short)f2bf(fmaxf(bf2f((u16)z8[2]) * ga.z + ba.z, 0.f));
    y[3] = (short)f2bf(fmaxf(bf2f((u16)z8[3]) * ga.w + ba.w, 0.f));
    y[4] = (short)f2bf(fmaxf(bf2f((u16)z8[4]) * gb.x + bb.x, 0.f));
    y[5] = (short)f2bf(fmaxf(bf2f((u16)z8[5]) * gb.y + bb.y, 0.f));
    y[6] = (short)f2bf(fmaxf(bf2f((u16)z8[6]) * gb.z + bb.z, 0.f));
    y[7] = (short)f2bf(fmaxf(bf2f((u16)z8[7]) * gb.w + bb.w, 0.f));
    *reinterpret_cast<short8*>(f2out + row * 256 + c * 8) = y;
  }
}

// Sum split-K partials + bias, LN over H, ReLU -> fp32 out.
// 250 blocks x 256 threads; 8 rows/block, 32 lanes/row, float4 loads
// (fully coalesced: 32 lanes x 8 floats = one 1KB row per instruction).
__global__ __launch_bounds__(256) void ln3_k(
    const float* __restrict__ partial,  // (SPLITK, N, H) fp32
    const float* __restrict__ b_out,
    const float* __restrict__ g3, const float* __restrict__ b3,
    float* __restrict__ out)            // (N, H) fp32
{
  const int n = blockIdx.x * 8 + (threadIdx.x >> 5);
  const int t = threadIdx.x & 31;
  const int h0 = t * 8;
  float4 xa = ((const float4*)(b_out + h0))[0];
  float4 xb = ((const float4*)(b_out + h0))[1];
#pragma unroll
  for (int ss = 0; ss < SPLITK; ++ss) {
    const float* pp = partial + ((long)ss * N_INST + n) * H_DIM + h0;
    float4 va = ((const float4*)pp)[0];
    float4 vb = ((const float4*)pp)[1];
    xa.x += va.x; xa.y += va.y; xa.z += va.z; xa.w += va.w;
    xb.x += vb.x; xb.y += vb.y; xb.z += vb.z; xb.w += vb.w;
  }
  float sv = xa.x + xa.y + xa.z + xa.w + xb.x + xb.y + xb.z + xb.w;
  float s2 = xa.x * xa.x + xa.y * xa.y + xa.z * xa.z + xa.w * xa.w +
             xb.x * xb.x + xb.y * xb.y + xb.z * xb.z + xb.w * xb.w;
#pragma unroll
  for (int m = 1; m < 32; m <<= 1) {
    sv += __shfl_xor(sv, m, 32);
    s2 += __shfl_xor(s2, m, 32);
  }
  float mean = sv * (1.f / 256.f);
  float var = s2 * (1.f / 256.f) - mean * mean;
  float rs = rsqrtf(var + LN_EPS);
  float4 ga = ((const float4*)(g3 + h0))[0];
  float4 gb = ((const float4*)(g3 + h0))[1];
  float4 ba = ((const float4*)(b3 + h0))[0];
  float4 bb = ((const float4*)(b3 + h0))[1];
  float4 ya, yb;
  ya.x = fmaxf((xa.x - mean) * rs * ga.x + ba.x, 0.f);
  ya.y = fmaxf((xa.y - mean) * rs * ga.y + ba.y, 0.f);
  ya.z = fmaxf((xa.z - mean) * rs * ga.z + ba.z, 0.f);
  ya.w = fmaxf((xa.w - mean) * rs * ga.w + ba.w, 0.f);
  yb.x = fmaxf((xb.x - mean) * rs * gb.x + bb.x, 0.f);
  yb.y = fmaxf((xb.y - mean) * rs * gb.y + bb.y, 0.f);
  yb.z = fmaxf((xb.z - mean) * rs * gb.z + bb.z, 0.f);
  yb.w = fmaxf((xb.w - mean) * rs * gb.w + bb.w, 0.f);
  float* op = out + (long)n * H_DIM + h0;
  ((float4*)op)[0] = ya;
  ((float4*)op)[1] = yb;
}

extern "C" void kernel_launch(void* const* d_in, const int* in_sizes, int n_in,
                              void* d_out, int out_size, void* d_ws, size_t ws_size,
                              hipStream_t stream) {
  const float* pro  = (const float*)d_in[0];
  const float* roi  = (const float*)d_in[1];
  const float* Wdyn = (const float*)d_in[2];
  const float* bdyn = (const float*)d_in[3];
  const float* Wout = (const float*)d_in[4];
  const float* bout = (const float*)d_in[5];
  const float* g1 = (const float*)d_in[6];
  const float* b1 = (const float*)d_in[7];
  const float* g2 = (const float*)d_in[8];
  const float* b2 = (const float*)d_in[9];
  const float* g3 = (const float*)d_in[10];
  const float* b3 = (const float*)d_in[11];
  float* out = (float*)d_out;

  // ws layout (bytes):
  //   proB  @ 0          : 1,024,000
  //   WdynT @ 1,024,000  : 16,777,216
  //   WoutT @ 17,801,216 : 6,422,528
  //   P12   @ 24,223,744 : 131,072,000 (2000 x [p1T|p2T]; partial aliases)
  //   f2n   @ 155,295,744: 50,176,000
  char* ws = (char*)d_ws;
  u16* proB  = (u16*)ws;
  u16* WdynT = (u16*)(ws + 1024000);
  u16* WoutT = (u16*)(ws + 17801216);
  u16* P12   = (u16*)(ws + 24223744);
  u16* f2n   = (u16*)(ws + 155295744);
  float* partial = (float*)(ws + 24223744);

  dim3 blk(256);

  // merged prep: wdyn transpose (2048) + wout transpose (784) + pro cast (500)
  prep_all<<<dim3(3332), blk, 0, stream>>>(pro, proB, Wdyn, WdynT, Wout, WoutT);

  // params: (2000x256)@(256x32768) -> P12[n][0..32768), ldc=32768
  gemm128<<<dim3(16 * 256, 1), blk, 0, stream>>>(
      proB, H_DIM, N_INST, WdynT, H_DIM, bdyn, 3,
      (void*)P12, 32768, 0L, 8, 256, 0);

  // fused bmm1+LN1+bmm2+LN2
  bmm12_ln<<<dim3(N_INST), blk, 0, stream>>>(roi, P12, g1, b1, g2, b2, f2n);

  // out GEMM: (2000x12544)@(12544x256), split-K=14 (28 ksteps)
  gemm128<<<dim3(16 * 2, SPLITK), blk, 0, stream>>>(
      f2n, R_DIM * H_DIM, N_INST, WoutT, R_DIM * H_DIM, nullptr, 0,
      (void*)partial, H_DIM, (long)N_INST * H_DIM, 28, 2, 1);

  ln3_k<<<dim3(250), blk, 0, stream>>>(partial, bout, g3, b3, out);
}

// Round 8
// 322.725 us; speedup vs baseline: 1.1169x; 1.0253x over previous
//
#include <hip/hip_runtime.h>

typedef unsigned short u16;
typedef __attribute__((ext_vector_type(8))) short short8;
typedef __attribute__((ext_vector_type(4))) float f32x4;

#define N_INST 2000
#define H_DIM 256
#define D_DIM 64
#define R_DIM 49
#define LN_EPS 1e-5f
#define SPLITK 14

__device__ __forceinline__ u16 f2bf(float f) {
  union { float f; unsigned int i; } x; x.f = f;
  unsigned int r = x.i + 0x7fffu + ((x.i >> 16) & 1u);  // RNE
  return (u16)(r >> 16);
}
__device__ __forceinline__ float bf2f(u16 u) {
  union { unsigned int i; float f; } x; x.i = ((unsigned int)u) << 16; return x.f;
}
__device__ __forceinline__ short8 ld8(const u16* p) {
  return *reinterpret_cast<const short8*>(p);
}
__device__ __forceinline__ short8 pack8(float4 a, float4 b) {
  short8 r;
  r[0] = (short)f2bf(a.x); r[1] = (short)f2bf(a.y);
  r[2] = (short)f2bf(a.z); r[3] = (short)f2bf(a.w);
  r[4] = (short)f2bf(b.x); r[5] = (short)f2bf(b.y);
  r[6] = (short)f2bf(b.z); r[7] = (short)f2bf(b.w);
  return r;
}
__device__ __forceinline__ f32x4 mfma16(short8 a, short8 b, f32x4 c) {
  return __builtin_amdgcn_mfma_f32_16x16x32_bf16(a, b, c, 0, 0, 0);
}
// async global->LDS, 16B per lane. LDS dest lane-linear (m104).
__device__ __forceinline__ void gload16(const u16* g, u16* l) {
  __builtin_amdgcn_global_load_lds(
      (const __attribute__((address_space(1))) void*)g,
      (__attribute__((address_space(3))) void*)l, 16, 0, 0);
}

// ---------------- merged prep kernel (one launch) ----------------
// blocks [0,2048): cast_wdyn (half = b>>10)
// blocks [2048,2832): cast_wout
// blocks [2832,3332): cast_pro (grid-stride)
__global__ __launch_bounds__(256) void prep_all(
    const float* __restrict__ pro,  u16* __restrict__ proB,
    const float* __restrict__ Wdyn, u16* __restrict__ WdynT,
    const float* __restrict__ Wout, u16* __restrict__ WoutT) {
  __shared__ u16 T[64][65];
  const int tid = threadIdx.x;
  const int wave = tid >> 6, lane = tid & 63;
  const int b = blockIdx.x;
  if (b < 2048) {
    // Wdyn (256 x 32768) fp32 -> WdynT bf16 transposed+permuted:
    //  half0: WdynT[d*256+h][k]      = Wdyn[k][h*64+d]
    //  half1: WdynT[16384+h*64+d][k] = Wdyn[k][16384+d*256+h]
    const int half = b >> 10;
    const int bb = b & 1023;
    const int kt = bb >> 8;
    long colbase, rowbase; int rstride;
    if (half == 0) {
      int h = bb & 255;
      colbase = (long)h * 64; rowbase = h; rstride = 256;
    } else {
      int d = bb & 63, hc = (bb >> 6) & 3;
      colbase = 16384L + d * 256 + hc * 64;
      rowbase = 16384L + hc * 4096 + d; rstride = 64;
    }
#pragma unroll
    for (int i = 0; i < 16; ++i) {
      int kk = wave * 16 + i;
      int k = kt * 64 + kk;
      T[kk][lane] = f2bf(Wdyn[(long)k * 32768 + colbase + lane]);
    }
    __syncthreads();
#pragma unroll
    for (int i = 0; i < 16; ++i) {
      int jj = wave * 16 + i;
      long ro = rowbase + (long)jj * rstride;
      WdynT[ro * 256 + kt * 64 + lane] = T[lane][jj];
    }
  } else if (b < 2832) {
    // Wout (12544 x 256) fp32 -> WoutT (256 x 12544) bf16
    const int b2 = b - 2048;
    const int kt = b2 >> 2, ct = b2 & 3;
#pragma unroll
    for (int i = 0; i < 16; ++i) {
      int kk = wave * 16 + i;
      long k = (long)kt * 64 + kk;
      T[kk][lane] = f2bf(Wout[k * 256 + ct * 64 + lane]);
    }
    __syncthreads();
#pragma unroll
    for (int i = 0; i < 16; ++i) {
      int cc = wave * 16 + i;
      long c = (long)ct * 64 + cc;
      WoutT[c * 12544 + (long)kt * 64 + lane] = T[lane][cc];
    }
  } else {
    // pro fp32 -> bf16, 512000 floats = 128000 float4
    const int n4 = 128000;
    for (int i = (b - 2832) * 256 + tid; i < n4; i += 500 * 256) {
      float4 v = ((const float4*)pro)[i];
      u16* op = proB + i * 4;
      op[0] = f2bf(v.x); op[1] = f2bf(v.y); op[2] = f2bf(v.z); op[3] = f2bf(v.w);
    }
  }
}

// ---------------- 128x128 GEMM, double-buffered staging (R2-proven) -------
// bias_mode: 0 direct, 3 combined dyn-perm (col<16384 p1-perm else p2-perm)
__global__ __launch_bounds__(256, 3) void gemm128(
    const u16* __restrict__ A, int lda, int M,
    const u16* __restrict__ BT, int ldbt,
    const float* __restrict__ bias, int bias_mode,
    void* __restrict__ Cout, int ldc, long c_stride_s,
    int ksteps, int n_blocks, int out_f32)
{
  union Smem {
    struct { u16 a[2][128 * 32]; u16 b[2][128 * 32]; } s;
    u16 cb[128 * 128];
  };
  __shared__ Smem sm;

  const int tid = threadIdx.x;
  const int wave = tid >> 6, lane = tid & 63;
  const int quad = lane >> 4, l16 = lane & 15;
  const int wm = wave >> 1, wn = wave & 1;
  const int bid = blockIdx.x;
  const int mblk = bid / n_blocks, nblk = bid - mblk * n_blocks;
  const int m0 = mblk * 128, n0 = nblk * 128;
  const int s = blockIdx.y;
  const int kb = s * ksteps * 32;

  const int cl = tid & 3;
  const int r0 = tid >> 2, r1 = 64 + (tid >> 2);
  const int cg0 = cl ^ ((r0 >> 1) & 3);
  const int cg1 = cl ^ ((r1 >> 1) & 3);
  int ga0 = m0 + r0; if (ga0 >= M) ga0 = M - 1;
  int ga1 = m0 + r1; if (ga1 >= M) ga1 = M - 1;
  const u16* gA0 = A + (long)ga0 * lda + kb + cg0 * 8;
  const u16* gA1 = A + (long)ga1 * lda + kb + cg1 * 8;
  const u16* gB0 = BT + (long)(n0 + r0) * ldbt + kb + cg0 * 8;
  const u16* gB1 = BT + (long)(n0 + r1) * ldbt + kb + cg1 * 8;

  int fAoff[4], fBoff[4];
#pragma unroll
  for (int i = 0; i < 4; ++i) {
    int rt = wm * 64 + i * 16 + l16;
    fAoff[i] = rt * 32 + (quad ^ ((rt >> 1) & 3)) * 8;
    int ct = wn * 64 + i * 16 + l16;
    fBoff[i] = ct * 32 + (quad ^ ((ct >> 1) & 3)) * 8;
  }

  f32x4 acc[4][4];
#pragma unroll
  for (int mi = 0; mi < 4; ++mi)
#pragma unroll
    for (int ni = 0; ni < 4; ++ni) acc[mi][ni] = f32x4{0.f, 0.f, 0.f, 0.f};

  gload16(gA0, &sm.s.a[0][tid * 8]);
  gload16(gA1, &sm.s.a[0][(tid + 256) * 8]);
  gload16(gB0, &sm.s.b[0][tid * 8]);
  gload16(gB1, &sm.s.b[0][(tid + 256) * 8]);

  for (int ks = 0; ks < ksteps; ++ks) {
    const int cur = ks & 1, nxt = cur ^ 1;
    __syncthreads();
    if (ks + 1 < ksteps) {
      const int ko = (ks + 1) * 32;
      gload16(gA0 + ko, &sm.s.a[nxt][tid * 8]);
      gload16(gA1 + ko, &sm.s.a[nxt][(tid + 256) * 8]);
      gload16(gB0 + ko, &sm.s.b[nxt][tid * 8]);
      gload16(gB1 + ko, &sm.s.b[nxt][(tid + 256) * 8]);
    }
    short8 av[4], bv[4];
#pragma unroll
    for (int i = 0; i < 4; ++i) {
      av[i] = ld8(&sm.s.a[cur][fAoff[i]]);
      bv[i] = ld8(&sm.s.b[cur][fBoff[i]]);
    }
#pragma unroll
    for (int mi = 0; mi < 4; ++mi)
#pragma unroll
      for (int ni = 0; ni < 4; ++ni)
        acc[mi][ni] = mfma16(av[mi], bv[ni], acc[mi][ni]);
  }

  if (!out_f32) {
    float bvv[4];
#pragma unroll
    for (int ni = 0; ni < 4; ++ni) {
      int col = n0 + wn * 64 + ni * 16 + l16;
      int bi = col;
      if (bias_mode == 3)
        bi = (col < 16384) ? (((col & 255) << 6) + (col >> 8))
                           : (16384 + ((col & 63) << 8) + ((col >> 6) & 255));
      bvv[ni] = bias ? bias[bi] : 0.f;
    }
    __syncthreads();
#pragma unroll
    for (int mi = 0; mi < 4; ++mi)
#pragma unroll
      for (int ni = 0; ni < 4; ++ni)
#pragma unroll
        for (int i = 0; i < 4; ++i) {
          int row = wm * 64 + mi * 16 + quad * 4 + i;
          int col = wn * 64 + ni * 16 + l16;
          sm.cb[row * 128 + col] = f2bf(acc[mi][ni][i] + bvv[ni]);
        }
    __syncthreads();
    u16* Cp = (u16*)Cout;
#pragma unroll
    for (int j = 0; j < 8; ++j) {
      int lin = j * 2048 + tid * 8;
      int row = lin >> 7, col = lin & 127;
      int grow = m0 + row;
      if (grow < M)
        *reinterpret_cast<short8*>(Cp + (long)grow * ldc + n0 + col) =
            ld8(&sm.cb[lin]);
    }
  } else {
    float* Cp = (float*)Cout + (long)s * c_stride_s;
#pragma unroll
    for (int mi = 0; mi < 4; ++mi)
#pragma unroll
      for (int ni = 0; ni < 4; ++ni) {
        int col = n0 + wn * 64 + ni * 16 + l16;
#pragma unroll
        for (int i = 0; i < 4; ++i) {
          int row = m0 + wm * 64 + mi * 16 + quad * 4 + i;
          if (row < M) Cp[(long)row * ldc + col] = acc[mi][ni][i];
        }
      }
  }
}

// ---------------- fused bmm1+LN1+bmm2+LN2 (R2 structure) ----------------
// One block per instance. P12[n] = [p1T [d][h] 32KB | p2T [h][d] 32KB].
// P2 is NOT LDS-staged: bmm2 is h-split across waves (wave w owns h in
// [64w,64w+64)); the wave's disjoint 8KB P2 slice loads global->VGPR
// (pf[4][2]) in the upfront burst. LDS = p1b 32K + f1b 8K = 40KB ->
// 4 blocks/CU. LN2 cross-wave reduce via stats in the dead tail of p1b.
__global__ __launch_bounds__(256, 4) void bmm12_ln(
    const float* __restrict__ roi,  // (R, N, H) fp32
    const u16* __restrict__ P12,    // (N, 32768) bf16
    const float* __restrict__ g1, const float* __restrict__ b1,
    const float* __restrict__ g2, const float* __restrict__ b2,
    u16* __restrict__ f2n)          // (N, R, H) bf16
{
  __shared__ __align__(16) u16 p1b[16384];  // 32 KB: P1 -> cb2 -> stats tail
  __shared__ __align__(16) u16 f1b[4096];   // 8 KB: LN1 output (swizzled)
  const int n = blockIdx.x;
  const int tid = threadIdx.x;
  const int wave = tid >> 6, lane = tid & 63;
  const int quad = lane >> 4, l16 = lane & 15;
  const int wstripe = wave * 16;

  // ---- upfront burst: P1 DMA -> p1b, roi -> regs (packed), P2 -> regs ----
  const u16* P1n = P12 + (long)n * 32768;
#pragma unroll
  for (int j = 0; j < 8; ++j) {
    int lc = j * 256 + tid;
    int d = lc >> 5, c = lc & 31;
    int cg = (c & 24) | ((c & 7) ^ (d & 7));
    gload16(P1n + d * 256 + cg * 8, &p1b[lc * 8]);
  }
  int r = wstripe + l16;
  int rr = (r < R_DIM) ? r : 0;
  const float* Arow = roi + ((long)rr * N_INST + n) * H_DIM + quad * 8;
  short8 sa[8];
#pragma unroll
  for (int ks = 0; ks < 8; ++ks) {
    float4 va = ((const float4*)(Arow + ks * 32))[0];
    float4 vb = ((const float4*)(Arow + ks * 32))[1];
    sa[ks] = pack8(va, vb);
  }
  const u16* P2n = P12 + (long)n * 32768 + 16384;
  short8 pf[4][2];
#pragma unroll
  for (int hs = 0; hs < 4; ++hs)
#pragma unroll
    for (int ks = 0; ks < 2; ++ks) {
      int h = wave * 64 + hs * 16 + l16;
      pf[hs][ks] = ld8(P2n + h * 64 + (ks * 4 + quad) * 8);
    }
  float gv1[4], bv1[4];
#pragma unroll
  for (int sub = 0; sub < 4; ++sub) {
    gv1[sub] = g1[sub * 16 + l16]; bv1[sub] = b1[sub * 16 + l16];
  }
  __syncthreads();  // barrier 1: p1b DMA drained

  // ---- bmm1: C1[r][d], wave stripe rows wstripe+0..15 ----
  f32x4 acc1[4];
#pragma unroll
  for (int i = 0; i < 4; ++i) acc1[i] = f32x4{0.f, 0.f, 0.f, 0.f};
#pragma unroll
  for (int ks = 0; ks < 8; ++ks) {
#pragma unroll
    for (int sub = 0; sub < 4; ++sub) {
      int d = sub * 16 + l16;
      int q = ks * 4 + quad;
      int c = (q & 24) | ((q & 7) ^ (d & 7));
      acc1[sub] = mfma16(sa[ks], ld8(&p1b[d * 256 + c * 8]), acc1[sub]);
    }
  }

  // ---- LN1 on acc1: stats over D=64 = (4 subs) x (16 lanes of quad) ----
  {
    float s1[4], s2[4];
#pragma unroll
    for (int i = 0; i < 4; ++i) {
      s1[i] = 0.f; s2[i] = 0.f;
#pragma unroll
      for (int sub = 0; sub < 4; ++sub) {
        float v = acc1[sub][i]; s1[i] += v; s2[i] += v * v;
      }
    }
#pragma unroll
    for (int m = 1; m < 16; m <<= 1)
#pragma unroll
      for (int i = 0; i < 4; ++i) {
        s1[i] += __shfl_xor(s1[i], m, 16);
        s2[i] += __shfl_xor(s2[i], m, 16);
      }
#pragma unroll
    for (int i = 0; i < 4; ++i) {
      float mean = s1[i] * (1.f / 64.f);
      float var = s2[i] * (1.f / 64.f) - mean * mean;
      float rs = rsqrtf(var + LN_EPS);
      int row = wstripe + quad * 4 + i;
#pragma unroll
      for (int sub = 0; sub < 4; ++sub) {
        float y = fmaxf((acc1[sub][i] - mean) * rs * gv1[sub] + bv1[sub], 0.f);
        int kc = (sub * 2 + (l16 >> 3)) ^ (row & 7);
        f1b[row * 64 + kc * 8 + (l16 & 7)] = f2bf(y);
      }
    }
  }
  __syncthreads();  // barrier 2: f1b visible to ALL waves (h-split bmm2)

  // ---- bmm2 (h-split): wave w computes C2[all 64 r][h in 64w..64w+63] ----
  f32x4 acc2[4][4];  // [rs][hs]
#pragma unroll
  for (int rs = 0; rs < 4; ++rs)
#pragma unroll
    for (int hs = 0; hs < 4; ++hs) acc2[rs][hs] = f32x4{0.f, 0.f, 0.f, 0.f};
#pragma unroll
  for (int ks = 0; ks < 2; ++ks) {
#pragma unroll
    for (int rs = 0; rs < 4; ++rs) {
      int row = rs * 16 + l16;
      int c2 = (ks * 4 + quad) ^ (row & 7);
      short8 af = ld8(&f1b[row * 64 + c2 * 8]);
#pragma unroll
      for (int hs = 0; hs < 4; ++hs)
        acc2[rs][hs] = mfma16(af, pf[hs][ks], acc2[rs][hs]);
    }
  }

  // ---- LN2: per-row stats over H=256, split across waves (64 h each) ----
  float s1[4][4], s2[4][4];
#pragma unroll
  for (int rs = 0; rs < 4; ++rs)
#pragma unroll
    for (int i = 0; i < 4; ++i) {
      float a = 0.f, b = 0.f;
#pragma unroll
      for (int hs = 0; hs < 4; ++hs) {
        float v = acc2[rs][hs][i]; a += v; b += v * v;
      }
      s1[rs][i] = a; s2[rs][i] = b;
    }
#pragma unroll
  for (int m = 1; m < 16; m <<= 1)
#pragma unroll
    for (int rs = 0; rs < 4; ++rs)
#pragma unroll
      for (int i = 0; i < 4; ++i) {
        s1[rs][i] += __shfl_xor(s1[rs][i], m, 16);
        s2[rs][i] += __shfl_xor(s2[rs][i], m, 16);
      }
  float2* lnst = reinterpret_cast<float2*>(&p1b[14336]);
  if (l16 == 0) {
#pragma unroll
    for (int rs = 0; rs < 4; ++rs)
#pragma unroll
      for (int i = 0; i < 4; ++i) {
        int row = rs * 16 + quad * 4 + i;
        lnst[row * 4 + wave] = float2{s1[rs][i], s2[rs][i]};
      }
  }
  __syncthreads();  // barrier 3: stats visible

  // ---- finalize LN2 + write normalized z -> cb2 (p1b, stride 264) ----
#pragma unroll
  for (int rs = 0; rs < 4; ++rs)
#pragma unroll
    for (int i = 0; i < 4; ++i) {
      int row = rs * 16 + quad * 4 + i;
      f32x4 qa = *reinterpret_cast<const f32x4*>(&lnst[row * 4]);
      f32x4 qb = *reinterpret_cast<const f32x4*>(&lnst[row * 4 + 2]);
      float S1 = qa[0] + qa[2] + qb[0] + qb[2];
      float S2 = qa[1] + qa[3] + qb[1] + qb[3];
      float mean = S1 * (1.f / 256.f);
      float var = S2 * (1.f / 256.f) - mean * mean;
      float rsq = rsqrtf(var + LN_EPS);
      if (row < R_DIM) {
#pragma unroll
        for (int hs = 0; hs < 4; ++hs)
          p1b[row * 264 + wave * 64 + hs * 16 + l16] =
              f2bf((acc2[rs][hs][i] - mean) * rsq);
      }
    }
  __syncthreads();  // barrier 4: cb2 visible

  // ---- epilogue copy: y = relu(z*g2 + b2), vectorized stores ----
  u16* f2out = f2n + (long)n * (R_DIM * H_DIM);
  for (int t = tid; t < R_DIM * 32; t += 256) {
    int row = t >> 5, c = t & 31;
    short8 z8 = ld8(&p1b[row * 264 + c * 8]);
    const float4* gp = (const float4*)(g2 + c * 8);
    const float4* bp = (const float4*)(b2 + c * 8);
    float4 ga = gp[0], gb = gp[1], ba = bp[0], bb = bp[1];
    short8 y;
    y[0] = (short)f2bf(fmaxf(bf2f((u16)z8[0]) * ga.x + ba.x, 0.f));
    y[1] = (short)f2bf(fmaxf(bf2f((u16)z8[1]) * ga.y + ba.y, 0.f));
    y[2] = (short)f2bf(fmaxf(bf2f((u16)z8[2]) * ga.z + ba.z, 0.f));
    y[3] = (short)f2bf(fmaxf(bf2f((u16)z8[3]) * ga.w + ba.w, 0.f));
    y[4] = (short)f2bf(fmaxf(bf2f((u16)z8[4]) * gb.x + bb.x, 0.f));
    y[5] = (short)f2bf(fmaxf(bf2f((u16)z8[5]) * gb.y + bb.y, 0.f));
    y[6] = (short)f2bf(fmaxf(bf2f((u16)z8[6]) * gb.z + bb.z, 0.f));
    y[7] = (short)f2bf(fmaxf(bf2f((u16)z8[7]) * gb.w + bb.w, 0.f));
    *reinterpret_cast<short8*>(f2out + row * 256 + c * 8) = y;
  }
}

// Sum split-K partials + bias, LN over H, ReLU -> fp32 out.
// 250 blocks x 256 threads; 8 rows/block, 32 lanes/row, float4 loads
// (fully coalesced: 32 lanes x 8 floats = one 1KB row per instruction).
__global__ __launch_bounds__(256) void ln3_k(
    const float* __restrict__ partial,  // (SPLITK, N, H) fp32
    const float* __restrict__ b_out,
    const float* __restrict__ g3, const float* __restrict__ b3,
    float* __restrict__ out)            // (N, H) fp32
{
  const int n = blockIdx.x * 8 + (threadIdx.x >> 5);
  const int t = threadIdx.x & 31;
  const int h0 = t * 8;
  float4 xa = ((const float4*)(b_out + h0))[0];
  float4 xb = ((const float4*)(b_out + h0))[1];
#pragma unroll
  for (int ss = 0; ss < SPLITK; ++ss) {
    const float* pp = partial + ((long)ss * N_INST + n) * H_DIM + h0;
    float4 va = ((const float4*)pp)[0];
    float4 vb = ((const float4*)pp)[1];
    xa.x += va.x; xa.y += va.y; xa.z += va.z; xa.w += va.w;
    xb.x += vb.x; xb.y += vb.y; xb.z += vb.z; xb.w += vb.w;
  }
  float sv = xa.x + xa.y + xa.z + xa.w + xb.x + xb.y + xb.z + xb.w;
  float s2 = xa.x * xa.x + xa.y * xa.y + xa.z * xa.z + xa.w * xa.w +
             xb.x * xb.x + xb.y * xb.y + xb.z * xb.z + xb.w * xb.w;
#pragma unroll
  for (int m = 1; m < 32; m <<= 1) {
    sv += __shfl_xor(sv, m, 32);
    s2 += __shfl_xor(s2, m, 32);
  }
  float mean = sv * (1.f / 256.f);
  float var = s2 * (1.f / 256.f) - mean * mean;
  float rs = rsqrtf(var + LN_EPS);
  float4 ga = ((const float4*)(g3 + h0))[0];
  float4 gb = ((const float4*)(g3 + h0))[1];
  float4 ba = ((const float4*)(b3 + h0))[0];
  float4 bb = ((const float4*)(b3 + h0))[1];
  float4 ya, yb;
  ya.x = fmaxf((xa.x - mean) * rs * ga.x + ba.x, 0.f);
  ya.y = fmaxf((xa.y - mean) * rs * ga.y + ba.y, 0.f);
  ya.z = fmaxf((xa.z - mean) * rs * ga.z + ba.z, 0.f);
  ya.w = fmaxf((xa.w - mean) * rs * ga.w + ba.w, 0.f);
  yb.x = fmaxf((xb.x - mean) * rs * gb.x + bb.x, 0.f);
  yb.y = fmaxf((xb.y - mean) * rs * gb.y + bb.y, 0.f);
  yb.z = fmaxf((xb.z - mean) * rs * gb.z + bb.z, 0.f);
  yb.w = fmaxf((xb.w - mean) * rs * gb.w + bb.w, 0.f);
  float* op = out + (long)n * H_DIM + h0;
  ((float4*)op)[0] = ya;
  ((float4*)op)[1] = yb;
}

extern "C" void kernel_launch(void* const* d_in, const int* in_sizes, int n_in,
                              void* d_out, int out_size, void* d_ws, size_t ws_size,
                              hipStream_t stream) {
  const float* pro  = (const float*)d_in[0];
  const float* roi  = (const float*)d_in[1];
  const float* Wdyn = (const float*)d_in[2];
  const float* bdyn = (const float*)d_in[3];
  const float* Wout = (const float*)d_in[4];
  const float* bout = (const float*)d_in[5];
  const float* g1 = (const float*)d_in[6];
  const float* b1 = (const float*)d_in[7];
  const float* g2 = (const float*)d_in[8];
  const float* b2 = (const float*)d_in[9];
  const float* g3 = (const float*)d_in[10];
  const float* b3 = (const float*)d_in[11];
  float* out = (float*)d_out;

  // ws layout (bytes):
  //   proB  @ 0          : 1,024,000
  //   WdynT @ 1,024,000  : 16,777,216
  //   WoutT @ 17,801,216 : 6,422,528
  //   P12   @ 24,223,744 : 131,072,000 (2000 x [p1T|p2T]; partial aliases)
  //   f2n   @ 155,295,744: 50,176,000
  char* ws = (char*)d_ws;
  u16* proB  = (u16*)ws;
  u16* WdynT = (u16*)(ws + 1024000);
  u16* WoutT = (u16*)(ws + 17801216);
  u16* P12   = (u16*)(ws + 24223744);
  u16* f2n   = (u16*)(ws + 155295744);
  float* partial = (float*)(ws + 24223744);

  dim3 blk(256);

  // merged prep: wdyn transpose (2048) + wout transpose (784) + pro cast (500)
  prep_all<<<dim3(3332), blk, 0, stream>>>(pro, proB, Wdyn, WdynT, Wout, WoutT);

  // params: (2000x256)@(256x32768) -> P12[n][0..32768), ldc=32768
  gemm128<<<dim3(16 * 256, 1), blk, 0, stream>>>(
      proB, H_DIM, N_INST, WdynT, H_DIM, bdyn, 3,
      (void*)P12, 32768, 0L, 8, 256, 0);

  // fused bmm1+LN1+bmm2+LN2
  bmm12_ln<<<dim3(N_INST), blk, 0, stream>>>(roi, P12, g1, b1, g2, b2, f2n);

  // out GEMM: (2000x12544)@(12544x256), split-K=14 (28 ksteps)
  gemm128<<<dim3(16 * 2, SPLITK), blk, 0, stream>>>(
      f2n, R_DIM * H_DIM, N_INST, WoutT, R_DIM * H_DIM, nullptr, 0,
      (void*)partial, H_DIM, (long)N_INST * H_DIM, 28, 2, 1);

  ln3_k<<<dim3(250), blk, 0, stream>>>(partial, bout, g3, b3, out);
}